// Round 7
// baseline (214.637 us; speedup 1.0000x reference)
//
#include <hip/hip_runtime.h>
#include <hip/hip_fp16.h>
#include <cstdint>

#define NCH 128   // IN_CH == OUT_CH == 128
#define NSLICE 8  // 8 col-slices of 16 ch: 100000*16*2B = 3.2 MB/slice < 4 MB L2/XCD

typedef short short8v __attribute__((ext_vector_type(8)));
typedef unsigned short ushort8v __attribute__((ext_vector_type(8)));
typedef unsigned short ushort4v __attribute__((ext_vector_type(4)));
typedef float f32x4  __attribute__((ext_vector_type(4)));

// f32 -> bf16 bits, round-to-nearest-even
static __device__ __forceinline__ short f2bf(float f) {
    unsigned u = __float_as_uint(f);
    u += 0x7FFFu + ((u >> 16) & 1u);
    return (short)(u >> 16);
}
static __device__ __forceinline__ unsigned short f2h(float f) {
    return __half_as_ushort(__float2half(f));
}
static __device__ __forceinline__ float h2f(unsigned short u) {
    return __half2float(__ushort_as_half(u));
}

// ---------------------------------------------------------------------------
// prep: a = softmax(attn_weights); Wpb[o][d] = bf16(W[o][d] * a[d])
// 128 blocks: block o handles output row o
// ---------------------------------------------------------------------------
__global__ __launch_bounds__(128)
void prep_kernel(const float* __restrict__ aw,
                 const float* __restrict__ W,
                 short* __restrict__ Wpb) {
    __shared__ float sa[NCH];
    const int t = threadIdx.x;
    const int o = blockIdx.x;
    sa[t] = aw[t];
    __syncthreads();
    float m = -1e30f;
#pragma unroll
    for (int d = 0; d < NCH; ++d) m = fmaxf(m, sa[d]);
    float s = 0.f;
#pragma unroll
    for (int d = 0; d < NCH; ++d) s += expf(sa[d] - m);
    const float av = expf(sa[t] - m) / s;
    Wpb[o * NCH + t] = f2bf(W[o * NCH + t] * av);
}

// ---------------------------------------------------------------------------
// node GEMM via MFMA 16x16x32 bf16, no LDS (round-6 winner, unchanged).
//   Ys[slice][node][c] = fp16( sum_d X[node][d] * Wp[slice*16+c][d] )
// mfma(a=Wfrag, b=Xfrag): D col = node, D row = channel -> packed 8B stores,
// per wave 16 nodes x 32B = contiguous 512B runs.
// ---------------------------------------------------------------------------
__global__ __launch_bounds__(256)
void node_gemm_mfma(const float* __restrict__ X,
                    const short* __restrict__ Wpb,
                    unsigned short* __restrict__ Ys, int M) {
    const int t    = threadIdx.x;
    const int wave = t >> 6;
    const int lane = t & 63;
    const int r    = lane & 15;
    const int kb   = lane >> 4;

    const int node  = blockIdx.x * 64 + wave * 16 + r;
    const int nodec = node < M ? node : M - 1;       // clamp; stores guarded
    const float* xr = X + (size_t)nodec * NCH;

    short8v b[4];
#pragma unroll
    for (int ks = 0; ks < 4; ++ks) {
        const float4 f0 = *reinterpret_cast<const float4*>(xr + ks * 32 + kb * 8);
        const float4 f1 = *reinterpret_cast<const float4*>(xr + ks * 32 + kb * 8 + 4);
        short8v v;
        v[0] = f2bf(f0.x); v[1] = f2bf(f0.y); v[2] = f2bf(f0.z); v[3] = f2bf(f0.w);
        v[4] = f2bf(f1.x); v[5] = f2bf(f1.y); v[6] = f2bf(f1.z); v[7] = f2bf(f1.w);
        b[ks] = v;
    }

#pragma unroll
    for (int tile = 0; tile < 8; ++tile) {
        f32x4 acc = {0.f, 0.f, 0.f, 0.f};
        const short* wr = Wpb + (size_t)(tile * 16 + r) * NCH;
#pragma unroll
        for (int ks = 0; ks < 4; ++ks) {
            const short8v a = *reinterpret_cast<const short8v*>(wr + ks * 32 + kb * 8);
            acc = __builtin_amdgcn_mfma_f32_16x16x32_bf16(a, b[ks], acc, 0, 0, 0);
        }
        if (node < M) {
            ushort4v h;
            h[0] = f2h(acc[0]); h[1] = f2h(acc[1]);
            h[2] = f2h(acc[2]); h[3] = f2h(acc[3]);
            *reinterpret_cast<ushort4v*>(
                Ys + (size_t)tile * M * 16 + (size_t)node * 16 + kb * 4) = h;
        }
    }
}

// ---------------------------------------------------------------------------
// sliced edge kernel, 16B-gather variant:
// out[e][slice*16+c] = relu(Ys[slice][src][c] + Ys[slice][tgt][c] + b[..])
// slice = blockIdx.x & 7 rides the XCD round-robin (L2-resident 3.2 MB slice).
// 2 lanes/edge (cl = half): each lane gathers a FULL 16B half-row of src and
// tgt -> gather+idx request count halves vs 4-lane shape. 128 edges/block.
// Store pattern unchanged: 2x16B NT per lane, 64B/edge segments @512B stride.
// ei via NT loads (streamed once per XCD; don't displace the Y slice).
// ---------------------------------------------------------------------------
__global__ __launch_bounds__(256)
void edge_out_sliced(const unsigned short* __restrict__ Ys,
                     const int* __restrict__ ei,
                     const float* __restrict__ bias,
                     float* __restrict__ out, int E, int M) {
    const unsigned bid = blockIdx.x;
    const int slice = bid & (NSLICE - 1);
    const int eblk  = bid >> 3;
    const int t  = threadIdx.x;
    const int e  = eblk * 128 + (t >> 1);
    const int cl = t & 1;                      // half-row: channels cl*8 .. +7
    if (e >= E) return;

    const int s = __builtin_nontemporal_load(ei + e);
    const int g = __builtin_nontemporal_load(ei + E + e);
    const unsigned short* base = Ys + (size_t)slice * M * 16 + cl * 8;

    const ushort8v hs = *reinterpret_cast<const ushort8v*>(base + (size_t)s * 16);
    const ushort8v ht = *reinterpret_cast<const ushort8v*>(base + (size_t)g * 16);
    const float4 vb0 = *reinterpret_cast<const float4*>(bias + slice * 16 + cl * 8);
    const float4 vb1 = *reinterpret_cast<const float4*>(bias + slice * 16 + cl * 8 + 4);

    f32x4 r0, r1;
    r0[0] = fmaxf(h2f(hs[0]) + h2f(ht[0]) + vb0.x, 0.f);
    r0[1] = fmaxf(h2f(hs[1]) + h2f(ht[1]) + vb0.y, 0.f);
    r0[2] = fmaxf(h2f(hs[2]) + h2f(ht[2]) + vb0.z, 0.f);
    r0[3] = fmaxf(h2f(hs[3]) + h2f(ht[3]) + vb0.w, 0.f);
    r1[0] = fmaxf(h2f(hs[4]) + h2f(ht[4]) + vb1.x, 0.f);
    r1[1] = fmaxf(h2f(hs[5]) + h2f(ht[5]) + vb1.y, 0.f);
    r1[2] = fmaxf(h2f(hs[6]) + h2f(ht[6]) + vb1.z, 0.f);
    r1[3] = fmaxf(h2f(hs[7]) + h2f(ht[7]) + vb1.w, 0.f);

    float* dstf = out + (size_t)e * NCH + slice * 16 + cl * 8;
    __builtin_nontemporal_store(r0, reinterpret_cast<f32x4*>(dstf));
    __builtin_nontemporal_store(r1, reinterpret_cast<f32x4*>(dstf + 4));
}

// ---------------------------------------------------------------------------
// fallback (only if ws too small): fully self-contained direct fp32 edge GEMM
// ---------------------------------------------------------------------------
__global__ __launch_bounds__(256)
void direct_edge_kernel(const float* __restrict__ X,
                        const int* __restrict__ ei,
                        const float* __restrict__ aw,
                        const float* __restrict__ W,
                        const float* __restrict__ bias,
                        float* __restrict__ out, int E) {
    __shared__ float sW[NCH][NCH + 1];
    __shared__ float sa[NCH];
    __shared__ float sE[8][NCH + 4];
    const int t = threadIdx.x;
    if (t < NCH) sa[t] = aw[t];
    __syncthreads();
    float m = -1e30f;
#pragma unroll
    for (int d = 0; d < NCH; ++d) m = fmaxf(m, sa[d]);
    float ssum = 0.f;
#pragma unroll
    for (int d = 0; d < NCH; ++d) ssum += expf(sa[d] - m);
    const float av = (t < NCH) ? expf(sa[t] - m) / ssum : 0.f;
    __syncthreads();
    if (t < NCH) sa[t] = av;
    __syncthreads();
    for (int i = t; i < NCH * 32; i += 256) {
        const int o = i >> 5, q = i & 31;
        float4 v = reinterpret_cast<const float4*>(W)[o * 32 + q];
        sW[o][q * 4 + 0] = v.x * sa[q * 4 + 0];
        sW[o][q * 4 + 1] = v.y * sa[q * 4 + 1];
        sW[o][q * 4 + 2] = v.z * sa[q * 4 + 2];
        sW[o][q * 4 + 3] = v.w * sa[q * 4 + 3];
    }
    __syncthreads();
    const int le = t >> 5, q = t & 31;
    for (int e0 = blockIdx.x * 8; e0 < E; e0 += gridDim.x * 8) {
        const int e = e0 + le;
        if (e < E) {
            const int s = ei[e];
            const int g = ei[E + e];
            const float4 vs = reinterpret_cast<const float4*>(X)[(size_t)s * 32 + q];
            const float4 vt = reinterpret_cast<const float4*>(X)[(size_t)g * 32 + q];
            sE[le][q * 4 + 0] = vs.x + vt.x;
            sE[le][q * 4 + 1] = vs.y + vt.y;
            sE[le][q * 4 + 2] = vs.z + vt.z;
            sE[le][q * 4 + 3] = vs.w + vt.w;
        }
        __syncthreads();
        if (e < E) {
            float a0 = 0.f, a1 = 0.f, a2 = 0.f, a3 = 0.f;
            const int o = q * 4;
#pragma unroll 4
            for (int d = 0; d < NCH; ++d) {
                const float x = sE[le][d];
                a0 += x * sW[o + 0][d];
                a1 += x * sW[o + 1][d];
                a2 += x * sW[o + 2][d];
                a3 += x * sW[o + 3][d];
            }
            float4 r;
            r.x = fmaxf(a0 + bias[o + 0], 0.f);
            r.y = fmaxf(a1 + bias[o + 1], 0.f);
            r.z = fmaxf(a2 + bias[o + 2], 0.f);
            r.w = fmaxf(a3 + bias[o + 3], 0.f);
            reinterpret_cast<float4*>(out)[(size_t)e * 32 + q] = r;
        }
        __syncthreads();
    }
}

// ---------------------------------------------------------------------------
extern "C" void kernel_launch(void* const* d_in, const int* in_sizes, int n_in,
                              void* d_out, int out_size, void* d_ws, size_t ws_size,
                              hipStream_t stream) {
    const float* X    = (const float*)d_in[0];   // [100000,128] f32
    const int*   ei   = (const int*)d_in[1];     // [2,625000] int32
    const float* aw   = (const float*)d_in[2];   // [128] f32
    const float* W    = (const float*)d_in[3];   // [128,128] f32
    const float* bias = (const float*)d_in[4];   // [128] f32
    float* out = (float*)d_out;

    const int M = in_sizes[0] / NCH;             // 100000 nodes
    const int E = in_sizes[1] / 2;               // 625000 edges

    const size_t y_off   = 65536;                                    // Wpb (32KB) + pad
    const size_t y_bytes = (size_t)M * NCH * sizeof(unsigned short); // 25.6 MB sliced

    if (ws_size >= y_off + y_bytes) {
        short* Wpb = (short*)d_ws;
        unsigned short* Ys = (unsigned short*)((char*)d_ws + y_off);
        prep_kernel<<<NCH, 128, 0, stream>>>(aw, W, Wpb);
        node_gemm_mfma<<<(M + 63) / 64, 256, 0, stream>>>(X, Wpb, Ys, M);
        const int eblks = (E + 127) / 128;
        edge_out_sliced<<<eblks * NSLICE, 256, 0, stream>>>(Ys, ei, bias, out, E, M);
    } else {
        int grid = (E + 7) / 8;
        if (grid > 32768) grid = 32768;
        direct_edge_kernel<<<grid, 256, 0, stream>>>(X, ei, aw, W, bias, out, E);
    }
}

// Round 8
// 158.045 us; speedup vs baseline: 1.3581x; 1.3581x over previous
//
#include <hip/hip_runtime.h>
#include <hip/hip_fp16.h>
#include <cstdint>

#define NCH 128   // IN_CH == OUT_CH == 128
#define NSLICE 8  // 8 col-slices of 16 ch: 100000*16*2B = 3.2 MB/slice < 4 MB L2/XCD

typedef short short8v __attribute__((ext_vector_type(8)));
typedef unsigned short ushort8v __attribute__((ext_vector_type(8)));
typedef unsigned short ushort4v __attribute__((ext_vector_type(4)));
typedef float f32x4  __attribute__((ext_vector_type(4)));

// f32 -> bf16 bits, round-to-nearest-even
static __device__ __forceinline__ short f2bf(float f) {
    unsigned u = __float_as_uint(f);
    u += 0x7FFFu + ((u >> 16) & 1u);
    return (short)(u >> 16);
}
static __device__ __forceinline__ unsigned short f2h(float f) {
    return __half_as_ushort(__float2half(f));
}
static __device__ __forceinline__ float h2f(unsigned short u) {
    return __half2float(__ushort_as_half(u));
}

// ---------------------------------------------------------------------------
// prep: a = softmax(attn_weights); Wpb[o][d] = bf16(W[o][d] * a[d])
// 128 blocks: block o handles output row o
// ---------------------------------------------------------------------------
__global__ __launch_bounds__(128)
void prep_kernel(const float* __restrict__ aw,
                 const float* __restrict__ W,
                 short* __restrict__ Wpb) {
    __shared__ float sa[NCH];
    const int t = threadIdx.x;
    const int o = blockIdx.x;
    sa[t] = aw[t];
    __syncthreads();
    float m = -1e30f;
#pragma unroll
    for (int d = 0; d < NCH; ++d) m = fmaxf(m, sa[d]);
    float s = 0.f;
#pragma unroll
    for (int d = 0; d < NCH; ++d) s += expf(sa[d] - m);
    const float av = expf(sa[t] - m) / s;
    Wpb[o * NCH + t] = f2bf(W[o * NCH + t] * av);
}

// ---------------------------------------------------------------------------
// node GEMM via MFMA 16x16x32 bf16, no LDS (round-6 winner, unchanged).
//   Ys[slice][node][c] = fp16( sum_d X[node][d] * Wp[slice*16+c][d] )
// mfma(a=Wfrag, b=Xfrag): D col = node, D row = channel -> packed 8B stores,
// per wave 16 nodes x 32B = contiguous 512B runs.
// ---------------------------------------------------------------------------
__global__ __launch_bounds__(256)
void node_gemm_mfma(const float* __restrict__ X,
                    const short* __restrict__ Wpb,
                    unsigned short* __restrict__ Ys, int M) {
    const int t    = threadIdx.x;
    const int wave = t >> 6;
    const int lane = t & 63;
    const int r    = lane & 15;
    const int kb   = lane >> 4;

    const int node  = blockIdx.x * 64 + wave * 16 + r;
    const int nodec = node < M ? node : M - 1;       // clamp; stores guarded
    const float* xr = X + (size_t)nodec * NCH;

    short8v b[4];
#pragma unroll
    for (int ks = 0; ks < 4; ++ks) {
        const float4 f0 = *reinterpret_cast<const float4*>(xr + ks * 32 + kb * 8);
        const float4 f1 = *reinterpret_cast<const float4*>(xr + ks * 32 + kb * 8 + 4);
        short8v v;
        v[0] = f2bf(f0.x); v[1] = f2bf(f0.y); v[2] = f2bf(f0.z); v[3] = f2bf(f0.w);
        v[4] = f2bf(f1.x); v[5] = f2bf(f1.y); v[6] = f2bf(f1.z); v[7] = f2bf(f1.w);
        b[ks] = v;
    }

#pragma unroll
    for (int tile = 0; tile < 8; ++tile) {
        f32x4 acc = {0.f, 0.f, 0.f, 0.f};
        const short* wr = Wpb + (size_t)(tile * 16 + r) * NCH;
#pragma unroll
        for (int ks = 0; ks < 4; ++ks) {
            const short8v a = *reinterpret_cast<const short8v*>(wr + ks * 32 + kb * 8);
            acc = __builtin_amdgcn_mfma_f32_16x16x32_bf16(a, b[ks], acc, 0, 0, 0);
        }
        if (node < M) {
            ushort4v h;
            h[0] = f2h(acc[0]); h[1] = f2h(acc[1]);
            h[2] = f2h(acc[2]); h[3] = f2h(acc[3]);
            *reinterpret_cast<ushort4v*>(
                Ys + (size_t)tile * M * 16 + (size_t)node * 16 + kb * 4) = h;
        }
    }
}

// ---------------------------------------------------------------------------
// sliced edge kernel, 16B-gather variant, NORMAL (cached) index loads:
// out[e][slice*16+c] = relu(Ys[slice][src][c] + Ys[slice][tgt][c] + b[..])
// slice = blockIdx.x & 7 rides the XCD round-robin (L2-resident 3.2 MB slice).
// 2 lanes/edge: each lane gathers a full 16B half-row of src and tgt.
// 128 edges/block. NT stores on out only (streaming; keep L2 for Y+ei).
// [r7 lesson: NT loads on ei bypass L2/L3 -> ~900cy per idx, 8x HBM re-fetch
//  of the index stream, kernel went latency-bound at 25% HBM. Never NT the
//  pointer-chase input.]
// ---------------------------------------------------------------------------
__global__ __launch_bounds__(256)
void edge_out_sliced(const unsigned short* __restrict__ Ys,
                     const int* __restrict__ ei,
                     const float* __restrict__ bias,
                     float* __restrict__ out, int E, int M) {
    const unsigned bid = blockIdx.x;
    const int slice = bid & (NSLICE - 1);
    const int eblk  = bid >> 3;
    const int t  = threadIdx.x;
    const int e  = eblk * 128 + (t >> 1);
    const int cl = t & 1;                      // half-row: channels cl*8 .. +7
    if (e >= E) return;

    const int s = ei[e];
    const int g = ei[E + e];
    const unsigned short* base = Ys + (size_t)slice * M * 16 + cl * 8;

    const ushort8v hs = *reinterpret_cast<const ushort8v*>(base + (size_t)s * 16);
    const ushort8v ht = *reinterpret_cast<const ushort8v*>(base + (size_t)g * 16);
    const float4 vb0 = *reinterpret_cast<const float4*>(bias + slice * 16 + cl * 8);
    const float4 vb1 = *reinterpret_cast<const float4*>(bias + slice * 16 + cl * 8 + 4);

    f32x4 r0, r1;
    r0[0] = fmaxf(h2f(hs[0]) + h2f(ht[0]) + vb0.x, 0.f);
    r0[1] = fmaxf(h2f(hs[1]) + h2f(ht[1]) + vb0.y, 0.f);
    r0[2] = fmaxf(h2f(hs[2]) + h2f(ht[2]) + vb0.z, 0.f);
    r0[3] = fmaxf(h2f(hs[3]) + h2f(ht[3]) + vb0.w, 0.f);
    r1[0] = fmaxf(h2f(hs[4]) + h2f(ht[4]) + vb1.x, 0.f);
    r1[1] = fmaxf(h2f(hs[5]) + h2f(ht[5]) + vb1.y, 0.f);
    r1[2] = fmaxf(h2f(hs[6]) + h2f(ht[6]) + vb1.z, 0.f);
    r1[3] = fmaxf(h2f(hs[7]) + h2f(ht[7]) + vb1.w, 0.f);

    float* dstf = out + (size_t)e * NCH + slice * 16 + cl * 8;
    __builtin_nontemporal_store(r0, reinterpret_cast<f32x4*>(dstf));
    __builtin_nontemporal_store(r1, reinterpret_cast<f32x4*>(dstf + 4));
}

// ---------------------------------------------------------------------------
// fallback (only if ws too small): fully self-contained direct fp32 edge GEMM
// ---------------------------------------------------------------------------
__global__ __launch_bounds__(256)
void direct_edge_kernel(const float* __restrict__ X,
                        const int* __restrict__ ei,
                        const float* __restrict__ aw,
                        const float* __restrict__ W,
                        const float* __restrict__ bias,
                        float* __restrict__ out, int E) {
    __shared__ float sW[NCH][NCH + 1];
    __shared__ float sa[NCH];
    __shared__ float sE[8][NCH + 4];
    const int t = threadIdx.x;
    if (t < NCH) sa[t] = aw[t];
    __syncthreads();
    float m = -1e30f;
#pragma unroll
    for (int d = 0; d < NCH; ++d) m = fmaxf(m, sa[d]);
    float ssum = 0.f;
#pragma unroll
    for (int d = 0; d < NCH; ++d) ssum += expf(sa[d] - m);
    const float av = (t < NCH) ? expf(sa[t] - m) / ssum : 0.f;
    __syncthreads();
    if (t < NCH) sa[t] = av;
    __syncthreads();
    for (int i = t; i < NCH * 32; i += 256) {
        const int o = i >> 5, q = i & 31;
        float4 v = reinterpret_cast<const float4*>(W)[o * 32 + q];
        sW[o][q * 4 + 0] = v.x * sa[q * 4 + 0];
        sW[o][q * 4 + 1] = v.y * sa[q * 4 + 1];
        sW[o][q * 4 + 2] = v.z * sa[q * 4 + 2];
        sW[o][q * 4 + 3] = v.w * sa[q * 4 + 3];
    }
    __syncthreads();
    const int le = t >> 5, q = t & 31;
    for (int e0 = blockIdx.x * 8; e0 < E; e0 += gridDim.x * 8) {
        const int e = e0 + le;
        if (e < E) {
            const int s = ei[e];
            const int g = ei[E + e];
            const float4 vs = reinterpret_cast<const float4*>(X)[(size_t)s * 32 + q];
            const float4 vt = reinterpret_cast<const float4*>(X)[(size_t)g * 32 + q];
            sE[le][q * 4 + 0] = vs.x + vt.x;
            sE[le][q * 4 + 1] = vs.y + vt.y;
            sE[le][q * 4 + 2] = vs.z + vt.z;
            sE[le][q * 4 + 3] = vs.w + vt.w;
        }
        __syncthreads();
        if (e < E) {
            float a0 = 0.f, a1 = 0.f, a2 = 0.f, a3 = 0.f;
            const int o = q * 4;
#pragma unroll 4
            for (int d = 0; d < NCH; ++d) {
                const float x = sE[le][d];
                a0 += x * sW[o + 0][d];
                a1 += x * sW[o + 1][d];
                a2 += x * sW[o + 2][d];
                a3 += x * sW[o + 3][d];
            }
            float4 r;
            r.x = fmaxf(a0 + bias[o + 0], 0.f);
            r.y = fmaxf(a1 + bias[o + 1], 0.f);
            r.z = fmaxf(a2 + bias[o + 2], 0.f);
            r.w = fmaxf(a3 + bias[o + 3], 0.f);
            reinterpret_cast<float4*>(out)[(size_t)e * 32 + q] = r;
        }
        __syncthreads();
    }
}

// ---------------------------------------------------------------------------
extern "C" void kernel_launch(void* const* d_in, const int* in_sizes, int n_in,
                              void* d_out, int out_size, void* d_ws, size_t ws_size,
                              hipStream_t stream) {
    const float* X    = (const float*)d_in[0];   // [100000,128] f32
    const int*   ei   = (const int*)d_in[1];     // [2,625000] int32
    const float* aw   = (const float*)d_in[2];   // [128] f32
    const float* W    = (const float*)d_in[3];   // [128,128] f32
    const float* bias = (const float*)d_in[4];   // [128] f32
    float* out = (float*)d_out;

    const int M = in_sizes[0] / NCH;             // 100000 nodes
    const int E = in_sizes[1] / 2;               // 625000 edges

    const size_t y_off   = 65536;                                    // Wpb (32KB) + pad
    const size_t y_bytes = (size_t)M * NCH * sizeof(unsigned short); // 25.6 MB sliced

    if (ws_size >= y_off + y_bytes) {
        short* Wpb = (short*)d_ws;
        unsigned short* Ys = (unsigned short*)((char*)d_ws + y_off);
        prep_kernel<<<NCH, 128, 0, stream>>>(aw, W, Wpb);
        node_gemm_mfma<<<(M + 63) / 64, 256, 0, stream>>>(X, Wpb, Ys, M);
        const int eblks = (E + 127) / 128;
        edge_out_sliced<<<eblks * NSLICE, 256, 0, stream>>>(Ys, ei, bias, out, E, M);
    } else {
        int grid = (E + 7) / 8;
        if (grid > 32768) grid = 32768;
        direct_edge_kernel<<<grid, 256, 0, stream>>>(X, ei, aw, W, bias, out, E);
    }
}

// Round 9
// 136.882 us; speedup vs baseline: 1.5680x; 1.1546x over previous
//
#include <hip/hip_runtime.h>
#include <hip/hip_fp16.h>
#include <cstdint>

#define NCH 128   // IN_CH == OUT_CH == 128
#define NGRP 4    // 4 col-groups of 32 ch -> 128B full-line out writes per edge

typedef short short8v __attribute__((ext_vector_type(8)));
typedef unsigned short ushort4v __attribute__((ext_vector_type(4)));
typedef float f32x4  __attribute__((ext_vector_type(4)));

// f32 -> bf16 bits, round-to-nearest-even
static __device__ __forceinline__ short f2bf(float f) {
    unsigned u = __float_as_uint(f);
    u += 0x7FFFu + ((u >> 16) & 1u);
    return (short)(u >> 16);
}
static __device__ __forceinline__ unsigned short f2h(float f) {
    return __half_as_ushort(__float2half(f));
}
static __device__ __forceinline__ float h2f(unsigned short u) {
    return __half2float(__ushort_as_half(u));
}

// ---------------------------------------------------------------------------
// prep: a = softmax(attn_weights); Wpb[o][d] = bf16(W[o][d] * a[d])
// ---------------------------------------------------------------------------
__global__ __launch_bounds__(128)
void prep_kernel(const float* __restrict__ aw,
                 const float* __restrict__ W,
                 short* __restrict__ Wpb) {
    __shared__ float sa[NCH];
    const int t = threadIdx.x;
    const int o = blockIdx.x;
    sa[t] = aw[t];
    __syncthreads();
    float m = -1e30f;
#pragma unroll
    for (int d = 0; d < NCH; ++d) m = fmaxf(m, sa[d]);
    float s = 0.f;
#pragma unroll
    for (int d = 0; d < NCH; ++d) s += expf(sa[d] - m);
    const float av = expf(sa[t] - m) / s;
    Wpb[o * NCH + t] = f2bf(W[o * NCH + t] * av);
}

// ---------------------------------------------------------------------------
// node GEMM via MFMA 16x16x32 bf16, no LDS (round-6 packed-store technique),
// output in GROUPED fp16 layout:
//   Yg[g][node][c] = fp16( sum_d X[node][d] * Wp[g*32+c][d] ),  g = tile>>1
// mfma(a=Wfrag, b=Xfrag): D col = node, D row = channel -> lane holds 4
// consecutive channels of one node = packed 8B store.
// ---------------------------------------------------------------------------
__global__ __launch_bounds__(256)
void node_gemm_mfma(const float* __restrict__ X,
                    const short* __restrict__ Wpb,
                    unsigned short* __restrict__ Yg, int M) {
    const int t    = threadIdx.x;
    const int wave = t >> 6;
    const int lane = t & 63;
    const int r    = lane & 15;
    const int kb   = lane >> 4;

    const int node  = blockIdx.x * 64 + wave * 16 + r;
    const int nodec = node < M ? node : M - 1;       // clamp; stores guarded
    const float* xr = X + (size_t)nodec * NCH;

    short8v b[4];
#pragma unroll
    for (int ks = 0; ks < 4; ++ks) {
        const float4 f0 = *reinterpret_cast<const float4*>(xr + ks * 32 + kb * 8);
        const float4 f1 = *reinterpret_cast<const float4*>(xr + ks * 32 + kb * 8 + 4);
        short8v v;
        v[0] = f2bf(f0.x); v[1] = f2bf(f0.y); v[2] = f2bf(f0.z); v[3] = f2bf(f0.w);
        v[4] = f2bf(f1.x); v[5] = f2bf(f1.y); v[6] = f2bf(f1.z); v[7] = f2bf(f1.w);
        b[ks] = v;
    }

#pragma unroll
    for (int tile = 0; tile < 8; ++tile) {
        f32x4 acc = {0.f, 0.f, 0.f, 0.f};
        const short* wr = Wpb + (size_t)(tile * 16 + r) * NCH;
#pragma unroll
        for (int ks = 0; ks < 4; ++ks) {
            const short8v a = *reinterpret_cast<const short8v*>(wr + ks * 32 + kb * 8);
            acc = __builtin_amdgcn_mfma_f32_16x16x32_bf16(a, b[ks], acc, 0, 0, 0);
        }
        // grouped layout: group = tile>>1, channel base = (tile&1)*16 + kb*4
        if (node < M) {
            ushort4v h;
            h[0] = f2h(acc[0]); h[1] = f2h(acc[1]);
            h[2] = f2h(acc[2]); h[3] = f2h(acc[3]);
            *reinterpret_cast<ushort4v*>(
                Yg + (size_t)(tile >> 1) * M * 32 + (size_t)node * 32
                   + (tile & 1) * 16 + kb * 4) = h;
        }
    }
}

// ---------------------------------------------------------------------------
// grouped edge kernel:
// out[e][g*32+c] = relu(Yg[g][src][c] + Yg[g][tgt][c] + b[g*32+c])
// group = blockIdx.x & 3 (XCD k always sees group k&3; working set 6.4 MB,
// ~60% L2 + L3 for the rest). 32 edges/block, 8 lanes/edge:
//   gather 2 x 8B per lane (8 lanes cover the full 64B row -> coalesced,
//   2 line-requests/edge), out = 8 lanes x 16B NT = 128B FULL-LINE per edge.
// idx loads CACHED (r7 lesson: never NT the pointer-chase input).
// ---------------------------------------------------------------------------
__global__ __launch_bounds__(256)
void edge_out_grp(const unsigned short* __restrict__ Yg,
                  const int* __restrict__ ei,
                  const float* __restrict__ bias,
                  float* __restrict__ out, int E, int M) {
    const unsigned bid = blockIdx.x;
    const int g    = bid & (NGRP - 1);
    const int eblk = bid >> 2;
    const int t  = threadIdx.x;
    const int e  = eblk * 32 + (t >> 3);
    const int cl = t & 7;                     // 8 lanes/edge, 4 ch each
    if (e >= E) return;

    const int s = ei[e];
    const int d = ei[E + e];
    const unsigned short* base = Yg + (size_t)g * M * 32 + cl * 4;

    const ushort4v hs = *reinterpret_cast<const ushort4v*>(base + (size_t)s * 32);
    const ushort4v ht = *reinterpret_cast<const ushort4v*>(base + (size_t)d * 32);
    const float4 vb = *reinterpret_cast<const float4*>(bias + g * 32 + cl * 4);

    f32x4 r;
    r[0] = fmaxf(h2f(hs[0]) + h2f(ht[0]) + vb.x, 0.f);
    r[1] = fmaxf(h2f(hs[1]) + h2f(ht[1]) + vb.y, 0.f);
    r[2] = fmaxf(h2f(hs[2]) + h2f(ht[2]) + vb.z, 0.f);
    r[3] = fmaxf(h2f(hs[3]) + h2f(ht[3]) + vb.w, 0.f);

    f32x4* dst = reinterpret_cast<f32x4*>(out + (size_t)e * NCH + g * 32 + cl * 4);
    __builtin_nontemporal_store(r, dst);
}

// ---------------------------------------------------------------------------
// fallback (only if ws too small): fully self-contained direct fp32 edge GEMM
// ---------------------------------------------------------------------------
__global__ __launch_bounds__(256)
void direct_edge_kernel(const float* __restrict__ X,
                        const int* __restrict__ ei,
                        const float* __restrict__ aw,
                        const float* __restrict__ W,
                        const float* __restrict__ bias,
                        float* __restrict__ out, int E) {
    __shared__ float sW[NCH][NCH + 1];
    __shared__ float sa[NCH];
    __shared__ float sE[8][NCH + 4];
    const int t = threadIdx.x;
    if (t < NCH) sa[t] = aw[t];
    __syncthreads();
    float m = -1e30f;
#pragma unroll
    for (int d = 0; d < NCH; ++d) m = fmaxf(m, sa[d]);
    float ssum = 0.f;
#pragma unroll
    for (int d = 0; d < NCH; ++d) ssum += expf(sa[d] - m);
    const float av = (t < NCH) ? expf(sa[t] - m) / ssum : 0.f;
    __syncthreads();
    if (t < NCH) sa[t] = av;
    __syncthreads();
    for (int i = t; i < NCH * 32; i += 256) {
        const int o = i >> 5, q = i & 31;
        float4 v = reinterpret_cast<const float4*>(W)[o * 32 + q];
        sW[o][q * 4 + 0] = v.x * sa[q * 4 + 0];
        sW[o][q * 4 + 1] = v.y * sa[q * 4 + 1];
        sW[o][q * 4 + 2] = v.z * sa[q * 4 + 2];
        sW[o][q * 4 + 3] = v.w * sa[q * 4 + 3];
    }
    __syncthreads();
    const int le = t >> 5, q = t & 31;
    for (int e0 = blockIdx.x * 8; e0 < E; e0 += gridDim.x * 8) {
        const int e = e0 + le;
        if (e < E) {
            const int s = ei[e];
            const int g = ei[E + e];
            const float4 vs = reinterpret_cast<const float4*>(X)[(size_t)s * 32 + q];
            const float4 vt = reinterpret_cast<const float4*>(X)[(size_t)g * 32 + q];
            sE[le][q * 4 + 0] = vs.x + vt.x;
            sE[le][q * 4 + 1] = vs.y + vt.y;
            sE[le][q * 4 + 2] = vs.z + vt.z;
            sE[le][q * 4 + 3] = vs.w + vt.w;
        }
        __syncthreads();
        if (e < E) {
            float a0 = 0.f, a1 = 0.f, a2 = 0.f, a3 = 0.f;
            const int o = q * 4;
#pragma unroll 4
            for (int d = 0; d < NCH; ++d) {
                const float x = sE[le][d];
                a0 += x * sW[o + 0][d];
                a1 += x * sW[o + 1][d];
                a2 += x * sW[o + 2][d];
                a3 += x * sW[o + 3][d];
            }
            float4 r;
            r.x = fmaxf(a0 + bias[o + 0], 0.f);
            r.y = fmaxf(a1 + bias[o + 1], 0.f);
            r.z = fmaxf(a2 + bias[o + 2], 0.f);
            r.w = fmaxf(a3 + bias[o + 3], 0.f);
            reinterpret_cast<float4*>(out)[(size_t)e * 32 + q] = r;
        }
        __syncthreads();
    }
}

// ---------------------------------------------------------------------------
extern "C" void kernel_launch(void* const* d_in, const int* in_sizes, int n_in,
                              void* d_out, int out_size, void* d_ws, size_t ws_size,
                              hipStream_t stream) {
    const float* X    = (const float*)d_in[0];   // [100000,128] f32
    const int*   ei   = (const int*)d_in[1];     // [2,625000] int32
    const float* aw   = (const float*)d_in[2];   // [128] f32
    const float* W    = (const float*)d_in[3];   // [128,128] f32
    const float* bias = (const float*)d_in[4];   // [128] f32
    float* out = (float*)d_out;

    const int M = in_sizes[0] / NCH;             // 100000 nodes
    const int E = in_sizes[1] / 2;               // 625000 edges

    const size_t y_off   = 65536;                                    // Wpb (32KB) + pad
    const size_t y_bytes = (size_t)M * NCH * sizeof(unsigned short); // 25.6 MB grouped

    if (ws_size >= y_off + y_bytes) {
        short* Wpb = (short*)d_ws;
        unsigned short* Yg = (unsigned short*)((char*)d_ws + y_off);
        prep_kernel<<<NCH, 128, 0, stream>>>(aw, W, Wpb);
        node_gemm_mfma<<<(M + 63) / 64, 256, 0, stream>>>(X, Wpb, Yg, M);
        const int eblks = (E + 31) / 32;
        edge_out_grp<<<eblks * NGRP, 256, 0, stream>>>(Yg, ei, bias, out, E, M);
    } else {
        int grid = (E + 7) / 8;
        if (grid > 32768) grid = 32768;
        direct_edge_kernel<<<grid, 256, 0, stream>>>(X, ei, aw, W, bias, out, E);
    }
}

// Round 10
// 125.962 us; speedup vs baseline: 1.7040x; 1.0867x over previous
//
#include <hip/hip_runtime.h>
#include <hip/hip_fp16.h>
#include <cstdint>

#define NCH 128   // IN_CH == OUT_CH == 128
#define NSLICE 8  // 8 col-slices of 16 ch: 100000*16*2B = 3.2 MB/slice < 4 MB L2/XCD

typedef short short8v __attribute__((ext_vector_type(8)));
typedef unsigned short ushort4v __attribute__((ext_vector_type(4)));
typedef float f32x4  __attribute__((ext_vector_type(4)));

// f32 -> bf16 bits, round-to-nearest-even
static __device__ __forceinline__ short f2bf(float f) {
    unsigned u = __float_as_uint(f);
    u += 0x7FFFu + ((u >> 16) & 1u);
    return (short)(u >> 16);
}
static __device__ __forceinline__ unsigned short f2h(float f) {
    return __half_as_ushort(__float2half(f));
}
static __device__ __forceinline__ float h2f(unsigned short u) {
    return __half2float(__ushort_as_half(u));
}

// ---------------------------------------------------------------------------
// prep: a = softmax(attn_weights); Wpb[o][d] = bf16(W[o][d] * a[d])
// ---------------------------------------------------------------------------
__global__ __launch_bounds__(128)
void prep_kernel(const float* __restrict__ aw,
                 const float* __restrict__ W,
                 short* __restrict__ Wpb) {
    __shared__ float sa[NCH];
    const int t = threadIdx.x;
    const int o = blockIdx.x;
    sa[t] = aw[t];
    __syncthreads();
    float m = -1e30f;
#pragma unroll
    for (int d = 0; d < NCH; ++d) m = fmaxf(m, sa[d]);
    float s = 0.f;
#pragma unroll
    for (int d = 0; d < NCH; ++d) s += expf(sa[d] - m);
    const float av = expf(sa[t] - m) / s;
    Wpb[o * NCH + t] = f2bf(W[o * NCH + t] * av);
}

// ---------------------------------------------------------------------------
// node GEMM via MFMA 16x16x32 bf16, no LDS (round-6 winner) + BIAS/2 FOLD:
//   Ys[slice][node][c] = fp16( sum_d X[node][d]*Wp[slice*16+c][d] + b[c]/2 )
// so the edge kernel computes relu(Y's + Y't) with no bias load.
// mfma(a=Wfrag, b=Xfrag): D col = node, D row = channel -> packed 8B stores.
// ---------------------------------------------------------------------------
__global__ __launch_bounds__(256)
void node_gemm_mfma(const float* __restrict__ X,
                    const short* __restrict__ Wpb,
                    const float* __restrict__ bias,
                    unsigned short* __restrict__ Ys, int M) {
    const int t    = threadIdx.x;
    const int wave = t >> 6;
    const int lane = t & 63;
    const int r    = lane & 15;
    const int kb   = lane >> 4;

    const int node  = blockIdx.x * 64 + wave * 16 + r;
    const int nodec = node < M ? node : M - 1;       // clamp; stores guarded
    const float* xr = X + (size_t)nodec * NCH;

    short8v b[4];
#pragma unroll
    for (int ks = 0; ks < 4; ++ks) {
        const float4 f0 = *reinterpret_cast<const float4*>(xr + ks * 32 + kb * 8);
        const float4 f1 = *reinterpret_cast<const float4*>(xr + ks * 32 + kb * 8 + 4);
        short8v v;
        v[0] = f2bf(f0.x); v[1] = f2bf(f0.y); v[2] = f2bf(f0.z); v[3] = f2bf(f0.w);
        v[4] = f2bf(f1.x); v[5] = f2bf(f1.y); v[6] = f2bf(f1.z); v[7] = f2bf(f1.w);
        b[ks] = v;
    }

#pragma unroll
    for (int tile = 0; tile < 8; ++tile) {
        f32x4 acc = {0.f, 0.f, 0.f, 0.f};
        const short* wr = Wpb + (size_t)(tile * 16 + r) * NCH;
#pragma unroll
        for (int ks = 0; ks < 4; ++ks) {
            const short8v a = *reinterpret_cast<const short8v*>(wr + ks * 32 + kb * 8);
            acc = __builtin_amdgcn_mfma_f32_16x16x32_bf16(a, b[ks], acc, 0, 0, 0);
        }
        if (node < M) {
            // fold half-bias for channels tile*16 + kb*4 .. +3
            const float4 vb = *reinterpret_cast<const float4*>(bias + tile * 16 + kb * 4);
            ushort4v h;
            h[0] = f2h(acc[0] + 0.5f * vb.x);
            h[1] = f2h(acc[1] + 0.5f * vb.y);
            h[2] = f2h(acc[2] + 0.5f * vb.z);
            h[3] = f2h(acc[3] + 0.5f * vb.w);
            *reinterpret_cast<ushort4v*>(
                Ys + (size_t)tile * M * 16 + (size_t)node * 16 + kb * 4) = h;
        }
    }
}

// ---------------------------------------------------------------------------
// sliced edge kernel (round-6 shape + 4-edge MLP batching, no bias load):
// out[e][slice*16+c] = relu(Ys[slice][src][c] + Ys[slice][tgt][c])
// slice = blockIdx.x & 7 rides the XCD round-robin (L2-resident 3.2 MB slice).
// 4 lanes/edge, 4 EDGES PER THREAD software-pipelined: 8 idx loads issued,
// then 8 gathers, then 4 NT stores -> 4x memory-level parallelism per thread.
// idx loads CACHED (r7: never NT the pointer-chase input).
// ---------------------------------------------------------------------------
__global__ __launch_bounds__(256)
void edge_out_sliced(const unsigned short* __restrict__ Ys,
                     const int* __restrict__ ei,
                     float* __restrict__ out, int E, int M) {
    const unsigned bid = blockIdx.x;
    const int slice = bid & (NSLICE - 1);
    const int eblk  = bid >> 3;
    const int t  = threadIdx.x;
    const int cl = t & 3;
    const int e0 = eblk * 256 + (t >> 2);      // edges e0 + k*64, k=0..3

    const unsigned short* base = Ys + (size_t)slice * M * 16 + cl * 4;

    int s[4], g[4];
#pragma unroll
    for (int k = 0; k < 4; ++k) {
        const int e = e0 + k * 64;
        const int ec = e < E ? e : 0;
        s[k] = ei[ec];
        g[k] = ei[E + ec];
    }
    ushort4v hs[4], ht[4];
#pragma unroll
    for (int k = 0; k < 4; ++k) {
        hs[k] = *reinterpret_cast<const ushort4v*>(base + (size_t)s[k] * 16);
        ht[k] = *reinterpret_cast<const ushort4v*>(base + (size_t)g[k] * 16);
    }
#pragma unroll
    for (int k = 0; k < 4; ++k) {
        const int e = e0 + k * 64;
        if (e < E) {
            f32x4 r;
            r[0] = fmaxf(h2f(hs[k][0]) + h2f(ht[k][0]), 0.f);
            r[1] = fmaxf(h2f(hs[k][1]) + h2f(ht[k][1]), 0.f);
            r[2] = fmaxf(h2f(hs[k][2]) + h2f(ht[k][2]), 0.f);
            r[3] = fmaxf(h2f(hs[k][3]) + h2f(ht[k][3]), 0.f);
            f32x4* dst = reinterpret_cast<f32x4*>(
                out + (size_t)e * NCH + slice * 16 + cl * 4);
            __builtin_nontemporal_store(r, dst);
        }
    }
}

// ---------------------------------------------------------------------------
// fallback (only if ws too small): fully self-contained direct fp32 edge GEMM
// ---------------------------------------------------------------------------
__global__ __launch_bounds__(256)
void direct_edge_kernel(const float* __restrict__ X,
                        const int* __restrict__ ei,
                        const float* __restrict__ aw,
                        const float* __restrict__ W,
                        const float* __restrict__ bias,
                        float* __restrict__ out, int E) {
    __shared__ float sW[NCH][NCH + 1];
    __shared__ float sa[NCH];
    __shared__ float sE[8][NCH + 4];
    const int t = threadIdx.x;
    if (t < NCH) sa[t] = aw[t];
    __syncthreads();
    float m = -1e30f;
#pragma unroll
    for (int d = 0; d < NCH; ++d) m = fmaxf(m, sa[d]);
    float ssum = 0.f;
#pragma unroll
    for (int d = 0; d < NCH; ++d) ssum += expf(sa[d] - m);
    const float av = (t < NCH) ? expf(sa[t] - m) / ssum : 0.f;
    __syncthreads();
    if (t < NCH) sa[t] = av;
    __syncthreads();
    for (int i = t; i < NCH * 32; i += 256) {
        const int o = i >> 5, q = i & 31;
        float4 v = reinterpret_cast<const float4*>(W)[o * 32 + q];
        sW[o][q * 4 + 0] = v.x * sa[q * 4 + 0];
        sW[o][q * 4 + 1] = v.y * sa[q * 4 + 1];
        sW[o][q * 4 + 2] = v.z * sa[q * 4 + 2];
        sW[o][q * 4 + 3] = v.w * sa[q * 4 + 3];
    }
    __syncthreads();
    const int le = t >> 5, q = t & 31;
    for (int e0 = blockIdx.x * 8; e0 < E; e0 += gridDim.x * 8) {
        const int e = e0 + le;
        if (e < E) {
            const int s = ei[e];
            const int g = ei[E + e];
            const float4 vs = reinterpret_cast<const float4*>(X)[(size_t)s * 32 + q];
            const float4 vt = reinterpret_cast<const float4*>(X)[(size_t)g * 32 + q];
            sE[le][q * 4 + 0] = vs.x + vt.x;
            sE[le][q * 4 + 1] = vs.y + vt.y;
            sE[le][q * 4 + 2] = vs.z + vt.z;
            sE[le][q * 4 + 3] = vs.w + vt.w;
        }
        __syncthreads();
        if (e < E) {
            float a0 = 0.f, a1 = 0.f, a2 = 0.f, a3 = 0.f;
            const int o = q * 4;
#pragma unroll 4
            for (int d = 0; d < NCH; ++d) {
                const float x = sE[le][d];
                a0 += x * sW[o + 0][d];
                a1 += x * sW[o + 1][d];
                a2 += x * sW[o + 2][d];
                a3 += x * sW[o + 3][d];
            }
            float4 r;
            r.x = fmaxf(a0 + bias[o + 0], 0.f);
            r.y = fmaxf(a1 + bias[o + 1], 0.f);
            r.z = fmaxf(a2 + bias[o + 2], 0.f);
            r.w = fmaxf(a3 + bias[o + 3], 0.f);
            reinterpret_cast<float4*>(out)[(size_t)e * 32 + q] = r;
        }
        __syncthreads();
    }
}

// ---------------------------------------------------------------------------
extern "C" void kernel_launch(void* const* d_in, const int* in_sizes, int n_in,
                              void* d_out, int out_size, void* d_ws, size_t ws_size,
                              hipStream_t stream) {
    const float* X    = (const float*)d_in[0];   // [100000,128] f32
    const int*   ei   = (const int*)d_in[1];     // [2,625000] int32
    const float* aw   = (const float*)d_in[2];   // [128] f32
    const float* W    = (const float*)d_in[3];   // [128,128] f32
    const float* bias = (const float*)d_in[4];   // [128] f32
    float* out = (float*)d_out;

    const int M = in_sizes[0] / NCH;             // 100000 nodes
    const int E = in_sizes[1] / 2;               // 625000 edges

    const size_t y_off   = 65536;                                    // Wpb (32KB) + pad
    const size_t y_bytes = (size_t)M * NCH * sizeof(unsigned short); // 25.6 MB sliced

    if (ws_size >= y_off + y_bytes) {
        short* Wpb = (short*)d_ws;
        unsigned short* Ys = (unsigned short*)((char*)d_ws + y_off);
        prep_kernel<<<NCH, 128, 0, stream>>>(aw, W, Wpb);
        node_gemm_mfma<<<(M + 63) / 64, 256, 0, stream>>>(X, Wpb, bias, Ys, M);
        const int eblks = (E + 255) / 256;
        edge_out_sliced<<<eblks * NSLICE, 256, 0, stream>>>(Ys, ei, out, E, M);
    } else {
        int grid = (E + 7) / 8;
        if (grid > 32768) grid = 32768;
        direct_edge_kernel<<<grid, 256, 0, stream>>>(X, ei, aw, W, bias, out, E);
    }
}